// Round 3
// baseline (199.360 us; speedup 1.0000x reference)
//
#include <hip/hip_runtime.h>
#include <hip/hip_bf16.h>

// GATv2Layer collapse: softmax rows sum to 1 => out = alpha*(h @ Wcat) + (1-alpha)*h.
// adj (128 MB fp32) is mathematically unused and never read.
// Inputs are FP32 (per reference dtypes); output FP32. Internally cast to bf16
// (RNE) for MFMA, accumulate fp32. Est. absmax ~0.02 << 0.076 threshold.
//
// R2 lesson: in_sizes[0] is NOT bytes -- deriving rows from it gave 4096 rows
// and left 3/4 of out at memset-zero (absmax 3.8 == max|ref|). Shapes are
// fixed by the problem (B=8, N=2048, F=256): hard-code rows = 16384.
//
// Geometry: each block covers 16 rows x 256 cols; the 16 col-tiles are split
// across 4 waves (4 each). Grid = 1024 blocks -> 4 blocks/CU, 16 waves/CU
// (4 waves/SIMD of latency hiding; the old 256-block layout was 1 wave/SIMD).

using bf16x8 = __attribute__((ext_vector_type(8))) __bf16;
using f32x4  = __attribute__((ext_vector_type(4))) float;

#define FDIM  256
#define DHEAD 64
#define ROWS  (8 * 2048)   // B*N, fixed by problem setup

// ---- Prep: W fp32 (H,F,D) -> Wt bf16 (H*D, F) so B-frags are 16B contiguous ----
__global__ __launch_bounds__(256) void wt_convert(const float* __restrict__ W,
                                                  __bf16* __restrict__ Wt) {
    // 256 blocks x 256 threads, one element each; coalesced fp32 read.
    const int head  = blockIdx.x >> 6;          // 0..3
    const int fbase = (blockIdx.x & 63) << 2;   // 0,4,...,252
    const int d     = threadIdx.x & 63;
    const int f     = fbase + (threadIdx.x >> 6);
    Wt[(head * DHEAD + d) * FDIM + f] = (__bf16)W[head * FDIM * DHEAD + f * DHEAD + d];
}

// ---- GEMM + residual. Block = 16 rows x 256 cols; wave = 16 rows x 64 cols. ----
__global__ __launch_bounds__(256) void gat_gemm(const float* __restrict__ h,
                                                const __bf16* __restrict__ Wt,
                                                const float* __restrict__ alpha_p,
                                                float* __restrict__ out) {
    const int lane = threadIdx.x & 63;
    const int wave = threadIdx.x >> 6;   // 0..3 -> col-tile group
    const int m    = lane & 15;          // A row / B col / D col selector
    const int quad = lane >> 4;          // 0..3
    const int r0   = blockIdx.x * 16;    // 16 rows per block

    const float alpha = alpha_p[0];
    const float beta  = 1.0f - alpha;

    // A fragments: lane holds A[m=lane&15][k=quad*8+j], j=0..7. Load fp32, cvt bf16.
    // All 4 waves load the same 16 rows (16 KB) -- L1 broadcast after first wave.
    bf16x8 a[8];
    const float* arow = h + (size_t)(r0 + m) * FDIM + quad * 8;
#pragma unroll
    for (int ks = 0; ks < 8; ++ks) {
        f32x4 lo = *reinterpret_cast<const f32x4*>(arow + ks * 32);
        f32x4 hi = *reinterpret_cast<const f32x4*>(arow + ks * 32 + 4);
        bf16x8 av;
#pragma unroll
        for (int j = 0; j < 4; ++j) {
            av[j]     = (__bf16)lo[j];
            av[4 + j] = (__bf16)hi[j];
        }
        a[ks] = av;
    }

    // Each wave owns 4 of the 16 col-tiles: ct = wave*4 .. wave*4+3.
#pragma unroll
    for (int t = 0; t < 4; ++t) {
        const int c0 = (wave * 4 + t) * 16;
        const int c  = c0 + m;
        f32x4 acc = {0.f, 0.f, 0.f, 0.f};
        // B layout: lane holds B[k=quad*8+j][n=lane&15] = Wt[c0+m][ks*32 + quad*8+j]
        const __bf16* brow = Wt + (c0 + m) * FDIM + quad * 8;
#pragma unroll
        for (int ks = 0; ks < 8; ++ks) {
            bf16x8 b = *reinterpret_cast<const bf16x8*>(brow + ks * 32);
            acc = __builtin_amdgcn_mfma_f32_16x16x32_bf16(a[ks], b, acc, 0, 0, 0);
        }
        // D layout: col = c0 + (lane&15), row = r0 + quad*4 + reg
#pragma unroll
        for (int reg = 0; reg < 4; ++reg) {
            const int r = r0 + quad * 4 + reg;
            const size_t idx = (size_t)r * FDIM + c;
            // out is write-once streaming: nontemporal store keeps Wt/h in L2.
            __builtin_nontemporal_store(alpha * acc[reg] + beta * h[idx], &out[idx]);
        }
    }
}

// ---- Fallback (no workspace): gather+convert B directly from fp32 W ----
__global__ __launch_bounds__(256) void gat_gemm_direct(const float* __restrict__ h,
                                                       const float* __restrict__ W,
                                                       const float* __restrict__ alpha_p,
                                                       float* __restrict__ out) {
    const int lane = threadIdx.x & 63;
    const int wave = threadIdx.x >> 6;
    const int m    = lane & 15;
    const int quad = lane >> 4;
    const int r0   = blockIdx.x * 16;

    const float alpha = alpha_p[0];
    const float beta  = 1.0f - alpha;

    bf16x8 a[8];
    const float* arow = h + (size_t)(r0 + m) * FDIM + quad * 8;
#pragma unroll
    for (int ks = 0; ks < 8; ++ks) {
        f32x4 lo = *reinterpret_cast<const f32x4*>(arow + ks * 32);
        f32x4 hi = *reinterpret_cast<const f32x4*>(arow + ks * 32 + 4);
        bf16x8 av;
#pragma unroll
        for (int j = 0; j < 4; ++j) {
            av[j]     = (__bf16)lo[j];
            av[4 + j] = (__bf16)hi[j];
        }
        a[ks] = av;
    }

#pragma unroll
    for (int t = 0; t < 4; ++t) {
        const int c0   = (wave * 4 + t) * 16;
        const int c    = c0 + m;
        const int head = c >> 6;
        const int dcol = c & 63;
        const float* wcol = W + head * FDIM * DHEAD + dcol;
        f32x4 acc = {0.f, 0.f, 0.f, 0.f};
#pragma unroll
        for (int ks = 0; ks < 8; ++ks) {
            bf16x8 b;
#pragma unroll
            for (int j = 0; j < 8; ++j)
                b[j] = (__bf16)wcol[(ks * 32 + quad * 8 + j) * DHEAD];
            acc = __builtin_amdgcn_mfma_f32_16x16x32_bf16(a[ks], b, acc, 0, 0, 0);
        }
#pragma unroll
        for (int reg = 0; reg < 4; ++reg) {
            const int r = r0 + quad * 4 + reg;
            const size_t idx = (size_t)r * FDIM + c;
            __builtin_nontemporal_store(alpha * acc[reg] + beta * h[idx], &out[idx]);
        }
    }
}

extern "C" void kernel_launch(void* const* d_in, const int* in_sizes, int n_in,
                              void* d_out, int out_size, void* d_ws, size_t ws_size,
                              hipStream_t stream) {
    const float* h       = (const float*)d_in[0];
    // d_in[1] = adj: unused (softmax row-sums are 1) -- never read.
    const float* W       = (const float*)d_in[2];
    const float* alpha_p = (const float*)d_in[3];
    float*       out     = (float*)d_out;

    const int nblk = ROWS / 16;   // 1024 blocks

    if (ws_size >= (size_t)(4 * FDIM * DHEAD * sizeof(__bf16))) {
        __bf16* Wt = (__bf16*)d_ws;
        wt_convert<<<256, 256, 0, stream>>>(W, Wt);
        gat_gemm<<<nblk, 256, 0, stream>>>(h, Wt, alpha_p, out);
    } else {
        gat_gemm_direct<<<nblk, 256, 0, stream>>>(h, W, alpha_p, out);
    }
}

// Round 4
// 197.869 us; speedup vs baseline: 1.0075x; 1.0075x over previous
//
#include <hip/hip_runtime.h>
#include <hip/hip_bf16.h>

// GATv2Layer collapse: softmax rows sum to 1 => out = alpha*(h @ Wcat) + (1-alpha)*h.
// adj (128 MB fp32) is mathematically unused and never read.
// Inputs are FP32 (per reference dtypes); output FP32. Internally cast to bf16
// (RNE) for MFMA, accumulate fp32. Measured absmax 0.0156 << 0.076 threshold.
//
// R3 lesson (rocprof): the harness re-poisons the 512 MiB WORKSPACE every timed
// iteration (__amd_rocclr_fillBufferAligned, 79 us @ 85% HBM peak, x2 per iter
// ~= 158 us of the 199 us total). Using d_ws at all costs ~40x the kernel's own
// math. Therefore: NO workspace. Single kernel, B-fragments gathered directly
// from fp32 W (256 KB -> L2-resident; ~8 us of chip-wide L2 traffic).
//
// Geometry: block = 16 rows x 256 cols, 16 col-tiles split across 4 waves.
// Grid = 1024 blocks -> 4 blocks/CU, 16 waves/CU (4 waves/SIMD latency hiding).

using bf16x8 = __attribute__((ext_vector_type(8))) __bf16;
using f32x4  = __attribute__((ext_vector_type(4))) float;

#define FDIM  256
#define DHEAD 64
#define ROWS  (8 * 2048)   // B*N, fixed by problem setup

// ---- GEMM + residual, direct W gather (no workspace, no prep kernel). ----
// Per-lane B-frag: b[j] = Wt[c][ks*32+quad*8+j] = W[head][ks*32+quad*8+j][dcol],
// identical index mapping to the verified Wt-based kernel (R3 passed absmax).
__global__ __launch_bounds__(256) void gat_gemm_direct(const float* __restrict__ h,
                                                       const float* __restrict__ W,
                                                       const float* __restrict__ alpha_p,
                                                       float* __restrict__ out) {
    const int lane = threadIdx.x & 63;
    const int wave = threadIdx.x >> 6;   // 0..3 -> col-tile group
    const int m    = lane & 15;          // A row / B col / D col selector
    const int quad = lane >> 4;          // 0..3
    const int r0   = blockIdx.x * 16;    // 16 rows per block

    const float alpha = alpha_p[0];
    const float beta  = 1.0f - alpha;

    // A fragments: lane holds A[m=lane&15][k=quad*8+j], j=0..7. fp32 load, cvt bf16.
    // All 4 waves touch the same 16 rows (16 KB) -- L1-shared after first wave.
    bf16x8 a[8];
    const float* arow = h + (size_t)(r0 + m) * FDIM + quad * 8;
#pragma unroll
    for (int ks = 0; ks < 8; ++ks) {
        f32x4 lo = *reinterpret_cast<const f32x4*>(arow + ks * 32);
        f32x4 hi = *reinterpret_cast<const f32x4*>(arow + ks * 32 + 4);
        bf16x8 av;
#pragma unroll
        for (int j = 0; j < 4; ++j) {
            av[j]     = (__bf16)lo[j];
            av[4 + j] = (__bf16)hi[j];
        }
        a[ks] = av;
    }

    // Each wave owns 4 of the 16 col-tiles: ct = wave*4 .. wave*4+3.
    // Col range wave*64..wave*64+63 == head `wave` exactly.
#pragma unroll
    for (int t = 0; t < 4; ++t) {
        const int c0   = (wave * 4 + t) * 16;
        const int c    = c0 + m;
        const int head = c >> 6;
        const int dcol = c & 63;
        const float* wcol = W + head * FDIM * DHEAD + dcol;
        f32x4 acc = {0.f, 0.f, 0.f, 0.f};
#pragma unroll
        for (int ks = 0; ks < 8; ++ks) {
            // 8 scalar fp32 gathers, stride 256 B; within a wave the 16 m-lanes
            // read 16 consecutive floats -> 4x 64 B segments per instruction.
            // All L2 hits (W = 256 KB total).
            bf16x8 b;
#pragma unroll
            for (int j = 0; j < 8; ++j)
                b[j] = (__bf16)wcol[(ks * 32 + quad * 8 + j) * DHEAD];
            acc = __builtin_amdgcn_mfma_f32_16x16x32_bf16(a[ks], b, acc, 0, 0, 0);
        }
        // D layout: col = c0 + (lane&15), row = r0 + quad*4 + reg.
        // Residual h[r][c] is within the block's 16 rows -> L1 hit.
#pragma unroll
        for (int reg = 0; reg < 4; ++reg) {
            const int r = r0 + quad * 4 + reg;
            const size_t idx = (size_t)r * FDIM + c;
            // out is write-once streaming: nontemporal store keeps h/W in cache.
            __builtin_nontemporal_store(alpha * acc[reg] + beta * h[idx], &out[idx]);
        }
    }
}

extern "C" void kernel_launch(void* const* d_in, const int* in_sizes, int n_in,
                              void* d_out, int out_size, void* d_ws, size_t ws_size,
                              hipStream_t stream) {
    const float* h       = (const float*)d_in[0];
    // d_in[1] = adj: unused (softmax row-sums are 1) -- never read.
    const float* W       = (const float*)d_in[2];
    const float* alpha_p = (const float*)d_in[3];
    float*       out     = (float*)d_out;

    // d_ws deliberately untouched: any workspace use triggers a 512 MiB
    // re-poison fill (~79 us) inside the harness's timed loop (R3 rocprof).
    (void)d_ws; (void)ws_size;

    const int nblk = ROWS / 16;   // 1024 blocks
    gat_gemm_direct<<<nblk, 256, 0, stream>>>(h, W, alpha_p, out);
}